// Round 17
// baseline (122.557 us; speedup 1.0000x reference)
//
#include <hip/hip_runtime.h>
#include <hip/hip_bf16.h>

#define B_   32
#define L_   2048
#define CIN  256
#define HID  512
#define TL   16
#define TPT  16                    // tiles per block = 256 rows
#define NGRP (B_ * L_ / (TL * TPT))// 256 row-groups of 256 rows
#define NBLK (NGRP * 2)            // x2 G-halves = 512 blocks = 2 per CU

// 2*log2(e): baked into Wc/bc so the gemm output feeds exp2 directly.
#define TANH_SCALE 2.885390081777927

typedef __bf16 bf16_t;
typedef __bf16 bf16x8 __attribute__((ext_vector_type(8)));
typedef __bf16 bf16x4 __attribute__((ext_vector_type(4)));
typedef float  f32x4  __attribute__((ext_vector_type(4)));

// LDS map (32 KB, packed): buf*16384 + pipe*8192 + row*512 (swizzled rows)
#define APIPE 8192u
#define ABUF  16384u

// ---------------------------------------------------------------------------
// Kernel 1: compose Wc = TANH_SCALE * (W2 @ W1) (fp32 -> bf16),
//           bc = TANH_SCALE * (W2 @ b1 + b2).
// No activation between the two 1x1 convs -> one projection, 3x fewer FLOPs.
// ---------------------------------------------------------------------------
__global__ void compose_kernel(const float* __restrict__ W1, const float* __restrict__ W2,
                               const float* __restrict__ b1, const float* __restrict__ b2,
                               bf16_t* __restrict__ Wc, float* __restrict__ bc)
{
    const int g0 = blockIdx.x * 8;       // 64 blocks
    const int c  = threadIdx.x;          // 256
    float acc[8] = {0.f, 0.f, 0.f, 0.f, 0.f, 0.f, 0.f, 0.f};
    for (int h = 0; h < HID; ++h) {
        const float w1 = W1[(size_t)h * CIN + c];   // coalesced row
#pragma unroll
        for (int k = 0; k < 8; ++k)                 // W2[g0+k][h]: uniform
            acc[k] = fmaf(W2[(size_t)(g0 + k) * HID + h], w1, acc[k]);
    }
#pragma unroll
    for (int k = 0; k < 8; ++k)
        Wc[(size_t)(g0 + k) * CIN + c] = (bf16_t)(acc[k] * (float)TANH_SCALE);
    if (c < 8) {
        const float* w2row = W2 + (size_t)(g0 + c) * HID;
        float t0 = 0.f, t1 = 0.f;
        for (int h = 0; h < HID; h += 2) {
            t0 = fmaf(w2row[h], b1[h], t0);
            t1 = fmaf(w2row[h + 1], b1[h + 1], t1);
        }
        bc[g0 + c] = (t0 + t1 + b2[g0 + c]) * (float)TANH_SCALE;
    }
}

// ---------------------------------------------------------------------------
// Kernel 2: fused GEMM + tanh-pair-product + row-reduction.
// R16 + the occupancy fix: R16 had NBLK=256 -> 1 block/CU -> 8 lockstep
// waves with every latency exposed (Occupancy 21%, MfmaUtil 14%). Now
// TPT=16 -> 512 blocks = 2/CU; LDS packed to 32 KB/block; ~88 total regs
// -> both blocks resident (16 waves/CU), naturally phase-shifted so one
// block's gemm covers the other's prefetch/tanh/barrier.
// Everything else proven: weights in registers (wreg 64), swizzled A dbuf
// (0 conflicts), G-split x2 adjacent pairing (L2 absorbs the dup x/y read,
// FETCH stayed 131 MB), bias+tanh-scale folded, 1 barrier/tile.
// swrite placed BEFORE the tanh tail: ds_writes drain under the VALU work.
// ---------------------------------------------------------------------------
__global__ __launch_bounds__(512, 2)
void fused_kernel(const float* __restrict__ x, const float* __restrict__ y,
                  const bf16_t* __restrict__ Wc, const float* __restrict__ bc,
                  float* __restrict__ partial)
{
    __shared__ char U[32768];            // packed A double-buffer

    const int tid  = threadIdx.x;
    const int lane = tid & 63;
    const int wv   = tid >> 6;           // wave 0..7
    const int l15  = lane & 15;
    const int l4   = lane >> 4;
    const int grp  = blockIdx.x >> 1;
    const int half = blockIdx.x & 1;
    const int gc0  = half * 256 + wv * 32;   // this wave's output-col base

    // --- hoist this wave's weight fragments into registers (stay resident)
    bf16x8 wreg[8][2];
#pragma unroll
    for (int kk = 0; kk < 8; ++kk)
#pragma unroll
        for (int cj = 0; cj < 2; ++cj)
            wreg[kk][cj] = *reinterpret_cast<const bf16x8*>(
                Wc + (size_t)(gc0 + cj * 16 + l15) * CIN + kk * 32 + l4 * 8);

    // bias fragments (scaled), folded into acc init each tile
    f32x4 bcv[2];
#pragma unroll
    for (int cj = 0; cj < 2; ++cj) {
        float4 t4 = *reinterpret_cast<const float4*>(bc + gc0 + cj * 16 + l4 * 4);
        bcv[cj] = (f32x4){t4.x, t4.y, t4.z, t4.w};
    }

    // staging identity: threads 0-255 stage x, 256-511 stage y; 16 thr/row
    const int sp = tid >> 8;
    const int t8 = tid & 255;
    const int sr = t8 >> 4;              // row 0..15
    const int sq = t8 & 15;              // float4 slot
    const unsigned sswz = (unsigned)((sr & 15) << 4);
    const unsigned soff = (unsigned)(sp * APIPE + sr * 512);
    const float* sptr = (sp ? y : x) + ((size_t)grp * (TPT * TL) + sr) * CIN;

    float4 v[4];
    auto sload = [&](const float* rowbase) {
        const float4* s4 = reinterpret_cast<const float4*>(rowbase);
#pragma unroll
        for (int c = 0; c < 4; ++c) v[c] = s4[sq + 16 * c];
    };
    auto swrite = [&](int buf) {
        char* p = U + (unsigned)(buf * ABUF) + soff;
#pragma unroll
        for (int c = 0; c < 4; ++c) {
            const int f = sq + 16 * c;
            bf16x4 h;
            h[0] = (bf16_t)v[c].x; h[1] = (bf16_t)v[c].y;
            h[2] = (bf16_t)v[c].z; h[3] = (bf16_t)v[c].w;
            *reinterpret_cast<bf16x4*>(p + (((unsigned)(8 * f)) ^ sswz)) = h;
        }
    };

    // A fragment base; per-kk addr = base ^ (kk<<6) (R11/R15-proven swizzle)
    const unsigned abase = (unsigned)(l15 * 512) + (((unsigned)(l4 * 16)) ^ ((unsigned)(l15 << 4)));

    f32x4 psum[2];
    psum[0] = (f32x4){0.f, 0.f, 0.f, 0.f};
    psum[1] = (f32x4){0.f, 0.f, 0.f, 0.f};

    // prologue: stage tile 0 into buf 0
    sload(sptr);
    swrite(0);
    __syncthreads();

    int cur = 0;
    for (int t = 0; t < TPT; ++t) {
        const bool pf = (t + 1 < TPT);
        if (pf) {                        // issue tile t+1 loads early (T14)
            sptr += TL * CIN;
            sload(sptr);
        }

        f32x4 accx[2], accy[2];
#pragma unroll
        for (int cj = 0; cj < 2; ++cj) { accx[cj] = bcv[cj]; accy[cj] = bcv[cj]; }

        const unsigned ab = (unsigned)(cur * ABUF);
#pragma unroll
        for (int kk = 0; kk < 8; ++kk) {
            const unsigned o = ab + (abase ^ (unsigned)(kk << 6));
            bf16x8 ax = *reinterpret_cast<const bf16x8*>(U + o);
            bf16x8 ay = *reinterpret_cast<const bf16x8*>(U + APIPE + o);
            __builtin_amdgcn_s_setprio(1);
            accx[0] = __builtin_amdgcn_mfma_f32_16x16x32_bf16(wreg[kk][0], ax, accx[0], 0, 0, 0);
            accy[0] = __builtin_amdgcn_mfma_f32_16x16x32_bf16(wreg[kk][0], ay, accy[0], 0, 0, 0);
            accx[1] = __builtin_amdgcn_mfma_f32_16x16x32_bf16(wreg[kk][1], ax, accx[1], 0, 0, 0);
            accy[1] = __builtin_amdgcn_mfma_f32_16x16x32_bf16(wreg[kk][1], ay, accy[1], 0, 0, 0);
            __builtin_amdgcn_s_setprio(0);
        }

        if (pf) swrite(cur ^ 1);         // ds_writes drain under the tanh tail

        // paired tanh product -> psum. Scale baked into Wc/bc: acc IS the
        // exp2 argument. tanh(a)tanh(b) = (Ea-1)(Eb-1)/((Ea+1)(Eb+1)).
#pragma unroll
        for (int cj = 0; cj < 2; ++cj)
#pragma unroll
            for (int r2 = 0; r2 < 4; ++r2) {
                float a = fminf(fmaxf(accx[cj][r2], -26.0f), 26.0f);
                float c = fminf(fmaxf(accy[cj][r2], -26.0f), 26.0f);
                float Ea = exp2f(a);
                float Eb = exp2f(c);
                float num = (Ea - 1.0f) * (Eb - 1.0f);
                float den = (Ea + 1.0f) * (Eb + 1.0f);
                psum[cj][r2] += num * __builtin_amdgcn_rcpf(den);
            }

        __syncthreads();                 // publish buf[cur^1]
        cur ^= 1;
    }

    // reduce the 16 row-lanes (l15 bits; l4 indexes the output col quad)
#pragma unroll
    for (int cj = 0; cj < 2; ++cj)
#pragma unroll
        for (int r2 = 0; r2 < 4; ++r2) {
            float s = psum[cj][r2];
            s += __shfl_xor(s, 1);
            s += __shfl_xor(s, 2);
            s += __shfl_xor(s, 4);
            s += __shfl_xor(s, 8);
            psum[cj][r2] = s;
        }
    if (l15 == 0) {
#pragma unroll
        for (int cj = 0; cj < 2; ++cj) {
            float4 o4 = make_float4(psum[cj][0], psum[cj][1], psum[cj][2], psum[cj][3]);
            *reinterpret_cast<float4*>(partial + (size_t)grp * HID + gc0 + cj * 16 + l4 * 4) = o4;
        }
    }
}

// ---------------------------------------------------------------------------
// Kernel 3: sum the 8 row-group partials per batch -> out[B][HID]
// (batch = 2048 rows = 8 groups of 256)
// ---------------------------------------------------------------------------
__global__ void reduce_kernel(const float* __restrict__ partial, float* __restrict__ out)
{
    int b = blockIdx.x;                  // 32
    int g = threadIdx.x;                 // 512
    float s = 0.f;
#pragma unroll
    for (int k = 0; k < 8; ++k)
        s += partial[((size_t)(b * 8 + k)) * HID + g];
    out[b * HID + g] = s;
}

extern "C" void kernel_launch(void* const* d_in, const int* in_sizes, int n_in,
                              void* d_out, int out_size, void* d_ws, size_t ws_size,
                              hipStream_t stream)
{
    const float* x  = (const float*)d_in[0];
    const float* y  = (const float*)d_in[1];
    const float* W1 = (const float*)d_in[2];
    const float* b1 = (const float*)d_in[3];
    const float* W2 = (const float*)d_in[4];
    const float* b2 = (const float*)d_in[5];
    float* out = (float*)d_out;

    char* ws = (char*)d_ws;
    bf16_t* Wc     = (bf16_t*)ws;                    // 256 KB
    float*  bc     = (float*)(ws + (256 << 10));     // 2 KB
    float*  partial = (float*)(ws + (264 << 10));    // 512 KB (256 grps x 512)

    hipLaunchKernelGGL(compose_kernel, dim3(HID / 8), dim3(CIN), 0, stream, W1, W2, b1, b2, Wc, bc);
    hipLaunchKernelGGL(fused_kernel, dim3(NBLK), dim3(512), 0, stream, x, y, Wc, bc, partial);
    hipLaunchKernelGGL(reduce_kernel, dim3(B_), dim3(512), 0, stream, partial, out);
}